// Round 12
// baseline (170.811 us; speedup 1.0000x reference)
//
#include <hip/hip_runtime.h>
#include <hip/hip_bf16.h>

// SelfAttention: N=2, S=2048, E=1024, H=16, D=64.
// Round 12: LDS-free attention. K/V fragments loaded per-lane straight from
// global (L2-resident: 512KB per (n,h)); no barriers, no staging, no
// conflicts; 4-wave blocks, 32q/wave, full kv range per wave; XCD-chunked
// bid swizzle keeps each (n,h)'s 16 blocks on one XCD. Q pre-scaled to bf16
// in prep. Softmax: fixed-max exp2, sign-AND masking, ones-MFMA rowsum
// (round 10's recipe). out_proj unchanged (round 10).

#define S_LEN  2048
#define EMB    1024
#define NHEAD  16
#define DHEAD  64
#define NBATCH 2

// log2(e)/32: folded into Q during prep so QK^T lands pre-scaled for exp2
#define KSC 0.04508422002778011f

typedef float              f32x4    __attribute__((ext_vector_type(4)));
typedef float              f32x16   __attribute__((ext_vector_type(16)));
typedef __bf16             bf16x8   __attribute__((ext_vector_type(8)));
typedef unsigned short     ushort8v __attribute__((ext_vector_type(8)));
typedef unsigned long long u64;

union FragU { ushort8v u; bf16x8 b; };
union BFrag { unsigned u32[4]; bf16x8 b; };

__device__ __forceinline__ unsigned short f2b(float f) {
  union { __hip_bfloat16 h; unsigned short u; } c;
  c.h = __float2bfloat16(f);
  return c.u;
}

__device__ __forceinline__ unsigned int cvt_pk_bf16(float lo, float hi) {
  unsigned int r;
  asm("v_cvt_pk_bf16_f32 %0, %1, %2" : "=v"(r) : "v"(lo), "v"(hi));
  return r;
}

#define PSWAP(a, b) asm("v_permlane32_swap_b32 %0, %1" : "+v"(a), "+v"(b))

#define GLD16(g, l)                                                            \
  __builtin_amdgcn_global_load_lds(                                            \
      (__attribute__((address_space(1))) void*)(g),                            \
      (__attribute__((address_space(3))) void*)(l), 16, 0, 0)

// ------------------------------------------------------- fused prep kernel
// [0,512): W cvt | [512,2560): K cvt | [2560,4608): Q cvt*KSC |
// [4608,5632): V transpose | [5632,13824): mask bitmap
__global__ __launch_bounds__(256) void prep(
    const float* __restrict__ Wo, unsigned short* __restrict__ Wb,
    const float* __restrict__ Kg, unsigned short* __restrict__ Kb,
    const float* __restrict__ Qg, unsigned short* __restrict__ Qb,
    const float* __restrict__ Vg, unsigned short* __restrict__ Vt,
    const int* __restrict__ Mg,   u64* __restrict__ Mb)
{
  const int bid = blockIdx.x;
  const int tid = threadIdx.x;
  if (bid < 4608) {
    const float* X; unsigned short* Y; int bb; float scl;
    if (bid < 512)       { X = Wo; Y = Wb; bb = bid;        scl = 1.f; }
    else if (bid < 2560) { X = Kg; Y = Kb; bb = bid - 512;  scl = 1.f; }
    else                 { X = Qg; Y = Qb; bb = bid - 2560; scl = KSC; }
    const size_t i = ((size_t)bb * 256 + tid) * 8;
    float4 a = *reinterpret_cast<const float4*>(X + i);
    float4 b = *reinterpret_cast<const float4*>(X + i + 4);
    ushort8v u;
    u[0] = f2b(a.x * scl); u[1] = f2b(a.y * scl); u[2] = f2b(a.z * scl); u[3] = f2b(a.w * scl);
    u[4] = f2b(b.x * scl); u[5] = f2b(b.y * scl); u[6] = f2b(b.z * scl); u[7] = f2b(b.w * scl);
    *reinterpret_cast<ushort8v*>(Y + i) = u;
  } else if (bid < 5632) {
    __shared__ unsigned short T[64][72];
    const int b2 = bid - 4608;
    const int sb = b2 & 31, h = (b2 >> 5) & 15, n = b2 >> 9;
    const int r = tid >> 2, cb = (tid & 3) * 16;
    const float* src = Vg + ((size_t)(n * S_LEN + sb * 64 + r)) * EMB + h * DHEAD + cb;
    ushort8v u0, u1;
#pragma unroll
    for (int j = 0; j < 2; ++j) {
      float4 x = *reinterpret_cast<const float4*>(src + j * 4);
      u0[j*4+0] = f2b(x.x); u0[j*4+1] = f2b(x.y); u0[j*4+2] = f2b(x.z); u0[j*4+3] = f2b(x.w);
      float4 y = *reinterpret_cast<const float4*>(src + 8 + j * 4);
      u1[j*4+0] = f2b(y.x); u1[j*4+1] = f2b(y.y); u1[j*4+2] = f2b(y.z); u1[j*4+3] = f2b(y.w);
    }
    *reinterpret_cast<ushort8v*>(&T[r][cb])     = u0;
    *reinterpret_cast<ushort8v*>(&T[r][cb + 8]) = u1;
    __syncthreads();
    const int d = tid >> 2, sc_ = (tid & 3) * 16;
    ushort8v o0, o1;
#pragma unroll
    for (int j = 0; j < 8; ++j) { o0[j] = T[sc_ + j][d]; o1[j] = T[sc_ + 8 + j][d]; }
    unsigned short* dst = Vt + ((size_t)((n * NHEAD + h) * DHEAD + d)) * S_LEN + sb * 64 + sc_;
    *reinterpret_cast<ushort8v*>(dst)     = o0;
    *reinterpret_cast<ushort8v*>(dst + 8) = o1;
  } else {
    const int b3 = bid - 5632;
    const size_t base = (size_t)b3 * 1024 + (tid >> 6) * 256;
    const int l = tid & 63;
#pragma unroll
    for (int j = 0; j < 4; ++j) {
      const int v = Mg[base + j * 64 + l];
      u64 bj = __ballot(v != 0);
      if (l == 0) Mb[base / 64 + j] = bj;
    }
  }
}

// ---------------------------------------------------------------- attention
// No LDS. Each wave: 32 q rows, all 2048 kv in 32 tiles of 64.
__global__ __launch_bounds__(256, 4) void attn_fwd(
    const unsigned short* __restrict__ Kb,   // bf16 [n][s][E]
    const unsigned short* __restrict__ Vtg,  // bf16 [n][h][d][s]
    const unsigned short* __restrict__ Qb,   // bf16 [n][s][E], pre-scaled
    const u64* __restrict__ Mbit,            // [n][s][32]
    unsigned short* __restrict__ Og)         // bf16 [n][s][E]
{
  const int bid0 = blockIdx.x;
  // XCD-chunked bijective swizzle (512 = 8 XCD x 64): XCD c gets orig [c*64, c*64+64)
  const int ob = ((bid0 & 7) << 6) | (bid0 >> 3);
  const int qb = ob & 15, h = (ob >> 4) & 15, n = ob >> 8;
  const int nh = n * NHEAD + h;
  const int tid = threadIdx.x;
  const int w = tid >> 6;
  const int l = tid & 63, q5 = l & 31, hi = l >> 5;
  const int hi4 = hi * 4;
  const int qg = qb * 128 + w * 32 + q5;   // this lane's global q row

  // Q fragments (B operand of 32x32x16): lane holds Q[qg][k=s*16+hi*8+j]
  FragU qf[4];
  {
    const unsigned short* qp = Qb + ((size_t)(n * S_LEN + qg)) * EMB + h * DHEAD + hi * 8;
#pragma unroll
    for (int s = 0; s < 4; ++s)
      qf[s].u = *reinterpret_cast<const ushort8v*>(qp + s * 16);
  }

  FragU ones;
#pragma unroll
  for (int j = 0; j < 8; ++j) ones.u[j] = 0x3F80;

  f32x16 acc0 = {}, acc1 = {}, racc = {};

  // per-lane global fragment bases
  // K: row = n*S + (it*64 + b*32 + q5), col bytes = h*128 + s*32 + hi*16
  const char* kbl = (const char*)Kb + ((size_t)(n * S_LEN) + q5) * 2048 + h * 128 + hi * 16;
  // V: row d = nh*64 + db*32 + q5 (4096B rows), col bytes = it*128 + slot*32 + hi*16
  const char* vbl = (const char*)Vtg + ((size_t)(nh * DHEAD) + q5) * 4096 + hi * 16;
  const u64* Mq = Mbit + ((size_t)(n * S_LEN) + qg) * 32;

#pragma unroll 2
  for (int it = 0; it < 32; ++it) {
    const u64 mrow = Mq[it];
    const char* kt = kbl + (size_t)it * 131072;   // 64 rows * 2048B
    const char* vt = vbl + (size_t)it * 128;
#pragma unroll
    for (int b = 0; b < 2; ++b) {
      // ---- QK^T: 4 direct-from-L2 fragment loads + 4 MFMAs ----
      f32x16 Sb = {};
#pragma unroll
      for (int s = 0; s < 4; ++s) {
        FragU kf;
        kf.u = *reinterpret_cast<const ushort8v*>(kt + b * 65536 + s * 32);
        Sb = __builtin_amdgcn_mfma_f32_32x32x16_bf16(kf.b, qf[s].b, Sb, 0, 0, 0);
      }
      // ---- fixed-max softmax (pre-scaled logits), sign-AND masking ----
      const unsigned m32_ = b ? (unsigned)(mrow >> 32) : (unsigned)mrow;
      float p_[16];
#pragma unroll
      for (int t = 0; t < 4; ++t) {
        const unsigned nib_ = m32_ >> (8 * t + hi4);
#pragma unroll
        for (int e = 0; e < 4; ++e) {
          const int r = 4 * t + e;
          float ex_ = __builtin_amdgcn_exp2f(Sb[r]);
          const unsigned sm_ = (unsigned)((int)(nib_ << (31 - e)) >> 31);
          p_[r] = __uint_as_float(__float_as_uint(ex_) & sm_);
        }
      }
      unsigned U0 = cvt_pk_bf16(p_[0],  p_[1]),  U1 = cvt_pk_bf16(p_[2],  p_[3]);
      unsigned U2 = cvt_pk_bf16(p_[4],  p_[5]),  U3 = cvt_pk_bf16(p_[6],  p_[7]);
      unsigned U4 = cvt_pk_bf16(p_[8],  p_[9]),  U5 = cvt_pk_bf16(p_[10], p_[11]);
      unsigned U6 = cvt_pk_bf16(p_[12], p_[13]), U7 = cvt_pk_bf16(p_[14], p_[15]);
      PSWAP(U0, U2); PSWAP(U1, U3); PSWAP(U4, U6); PSWAP(U5, U7);
      BFrag F0, F1;
      F0.u32[0] = U0; F0.u32[1] = U1; F0.u32[2] = U2; F0.u32[3] = U3;
      F1.u32[0] = U4; F1.u32[1] = U5; F1.u32[2] = U6; F1.u32[3] = U7;
      // ---- rowsum (ones-MFMA) + PV with direct-from-L2 V fragments ----
      racc = __builtin_amdgcn_mfma_f32_32x32x16_bf16(ones.b, F0.b, racc, 0, 0, 0);
      racc = __builtin_amdgcn_mfma_f32_32x32x16_bf16(ones.b, F1.b, racc, 0, 0, 0);
#pragma unroll
      for (int db = 0; db < 2; ++db) {
        FragU vf0, vf1;
        vf0.u = *reinterpret_cast<const ushort8v*>(vt + db * 131072 + (2 * b) * 32);
        vf1.u = *reinterpret_cast<const ushort8v*>(vt + db * 131072 + (2 * b + 1) * 32);
        if (db == 0) {
          acc0 = __builtin_amdgcn_mfma_f32_32x32x16_bf16(vf0.b, F0.b, acc0, 0, 0, 0);
          acc0 = __builtin_amdgcn_mfma_f32_32x32x16_bf16(vf1.b, F1.b, acc0, 0, 0, 0);
        } else {
          acc1 = __builtin_amdgcn_mfma_f32_32x32x16_bf16(vf0.b, F0.b, acc1, 0, 0, 0);
          acc1 = __builtin_amdgcn_mfma_f32_32x32x16_bf16(vf1.b, F1.b, acc1, 0, 0, 0);
        }
      }
    }
  }

  // ---- normalize + store (no combine: each wave owns full kv range) ----
  const float rin = 1.0f / racc[0];   // ones-MFMA: every C row holds full kv-sum
  unsigned short* orow = Og + ((size_t)(n * S_LEN + qg)) * EMB + h * DHEAD + hi4;
#pragma unroll
  for (int db = 0; db < 2; ++db) {
#pragma unroll
    for (int t = 0; t < 4; ++t) {
      float a0, a1, a2, a3;
      if (db == 0) {
        a0 = acc0[4*t] * rin;   a1 = acc0[4*t+1] * rin;
        a2 = acc0[4*t+2] * rin; a3 = acc0[4*t+3] * rin;
      } else {
        a0 = acc1[4*t] * rin;   a1 = acc1[4*t+1] * rin;
        a2 = acc1[4*t+2] * rin; a3 = acc1[4*t+3] * rin;
      }
      uint2 pk;
      pk.x = cvt_pk_bf16(a0, a1);
      pk.y = cvt_pk_bf16(a2, a3);
      *reinterpret_cast<uint2*>(orow + db * 32 + t * 8) = pk;
    }
  }
}

// ---------------------------------------------------------------- projection
__global__ __launch_bounds__(256) void out_proj(
    const unsigned short* __restrict__ A,   // bf16 [4096][1024]
    const unsigned short* __restrict__ W,   // bf16 [1024][1024]
    const float* __restrict__ bias,
    float* __restrict__ Y)                  // f32 [4096][1024]
{
  __shared__ __attribute__((aligned(16))) unsigned short At[2][8192];
  __shared__ __attribute__((aligned(16))) unsigned short Bt[2][4096];

  const int bid = blockIdx.x;
  const int nb = bid & 15, mb = bid >> 4;
  const int tid = threadIdx.x;
  const int w = tid >> 6, l = tid & 63, lg = l >> 4, li = l & 15;
  const int m0 = mb * 128, n0 = nb * 64;

  f32x4 acc[2][4];
#pragma unroll
  for (int g = 0; g < 2; ++g)
#pragma unroll
    for (int c = 0; c < 4; ++c) acc[g][c] = (f32x4){0.f, 0.f, 0.f, 0.f};

  const int srow8  = tid >> 3;
  const int schunk = (tid & 7) * 16;
  const int ssw    = (srow8 & 7) << 4;
  const char* abase = (const char*)A + ((size_t)m0 + srow8) * (EMB * 2) + (schunk ^ ssw);
  const char* bbase = (const char*)W + ((size_t)n0 + srow8) * (EMB * 2) + (schunk ^ ssw);
  const int rsw = (li & 7) << 4;

#define PROJ_STAGE(BUF, KK) do {                                               \
    const char* ab_ = abase + (KK) * 128;                                      \
    const char* bb_ = bbase + (KK) * 128;                                      \
    GLD16(ab_,             (char*)At + (BUF) * 16384 + w * 1024);              \
    GLD16(ab_ + 32 * 2048, (char*)At + (BUF) * 16384 + 4096 + w * 1024);       \
    GLD16(ab_ + 64 * 2048, (char*)At + (BUF) * 16384 + 8192 + w * 1024);       \
    GLD16(ab_ + 96 * 2048, (char*)At + (BUF) * 16384 + 12288 + w * 1024);      \
    GLD16(bb_,             (char*)Bt + (BUF) * 8192 + w * 1024);               \
    GLD16(bb_ + 32 * 2048, (char*)Bt + (BUF) * 8192 + 4096 + w * 1024);        \
  } while (0)

#define PROJ_TILE(BUF, KK) do {                                                \
    __syncthreads();                                                           \
    if ((KK) + 1 < 16) PROJ_STAGE((BUF) ^ 1, (KK) + 1);                        \
    __builtin_amdgcn_s_setprio(1);                                             \
    _Pragma("unroll") for (int s = 0; s < 2; ++s) {                            \
      FragU af_[2];                                                            \
      _Pragma("unroll") for (int g = 0; g < 2; ++g)                            \
        af_[g].u = *reinterpret_cast<const ushort8v*>(                         \
            (char*)At + (BUF) * 16384 +                                        \
            ((w * 32 + g * 16 + li) * 128 + ((s * 64 + lg * 16) ^ rsw)));      \
      _Pragma("unroll") for (int c = 0; c < 4; ++c) {                          \
        FragU bf_;                                                             \
        bf_.u = *reinterpret_cast<const ushort8v*>(                            \
            (char*)Bt + (BUF) * 8192 +                                         \
            ((c * 16 + li) * 128 + ((s * 64 + lg * 16) ^ rsw)));               \
        acc[0][c] = __builtin_amdgcn_mfma_f32_16x16x32_bf16(af_[0].b, bf_.b, acc[0][c], 0, 0, 0); \
        acc[1][c] = __builtin_amdgcn_mfma_f32_16x16x32_bf16(af_[1].b, bf_.b, acc[1][c], 0, 0, 0); \
      }                                                                        \
    }                                                                          \
    __builtin_amdgcn_s_setprio(0);                                             \
  } while (0)

  PROJ_STAGE(0, 0);
  for (int kk = 0; kk < 16; kk += 2) {
    PROJ_TILE(0, kk);
    PROJ_TILE(1, kk + 1);
  }

#pragma unroll
  for (int g = 0; g < 2; ++g)
#pragma unroll
    for (int c = 0; c < 4; ++c) {
      const float bv = bias[n0 + c * 16 + li];
#pragma unroll
      for (int r = 0; r < 4; ++r) {
        const int row = m0 + w * 32 + g * 16 + lg * 4 + r;
        Y[(size_t)row * EMB + n0 + c * 16 + li] = acc[g][c][r] + bv;
      }
    }
}

// ---------------------------------------------------------------- launch
extern "C" void kernel_launch(void* const* d_in, const int* in_sizes, int n_in,
                              void* d_out, int out_size, void* d_ws, size_t ws_size,
                              hipStream_t stream) {
  const float* Vg = (const float*)d_in[0];
  const float* Kg = (const float*)d_in[1];
  const float* Qg = (const float*)d_in[2];
  const int*   Mg = (const int*)d_in[3];
  const float* Wo = (const float*)d_in[4];
  const float* bo = (const float*)d_in[5];
  float* Y = (float*)d_out;

  char* ws = (char*)d_ws;
  unsigned short* Og   = (unsigned short*)(ws);                       //  8 MB
  unsigned short* Wb   = (unsigned short*)(ws + (8u << 20));          //  2 MB
  unsigned short* Kb16 = (unsigned short*)(ws + (10u << 20));         //  8 MB
  unsigned short* Vt   = (unsigned short*)(ws + (18u << 20));         //  8 MB
  u64*            Mbit = (u64*)(ws + (26u << 20));                    //  1 MB
  unsigned short* Qb16 = (unsigned short*)(ws + (27u << 20));         //  8 MB

  hipLaunchKernelGGL(prep, dim3(13824), dim3(256), 0, stream,
                     Wo, Wb, Kg, Kb16, Qg, Qb16, Vg, Vt, Mg, Mbit);
  hipLaunchKernelGGL(attn_fwd, dim3(NBATCH * NHEAD * (S_LEN / 128)), dim3(256), 0, stream,
                     Kb16, Vt, Qb16, Mbit, Og);
  hipLaunchKernelGGL(out_proj, dim3((NBATCH * S_LEN / 128) * (EMB / 64)), dim3(256), 0, stream,
                     Og, Wb, bo, Y);
}

// Round 13
// 94.787 us; speedup vs baseline: 1.8021x; 1.8021x over previous
//
#include <hip/hip_runtime.h>
#include <hip/hip_bf16.h>

// SelfAttention: N=2, S=2048, E=1024, H=16, D=64.
// Round 13: r11 wide-phase attn tile + amdgpu_waves_per_eu(4,4) to pin the
// 128-VGPR budget (r11 spilled at 64). out_proj: 128x128xBK64 tile, 2x
// MFMA:DS ratio. prep = round 10. Softmax recipe unchanged (pre-scaled Q,
// ones-MFMA rowsum, sign-AND masking).

#define S_LEN  2048
#define EMB    1024
#define NHEAD  16
#define DHEAD  64
#define NBATCH 2

// log2(e)/32: folded into Q so QK^T lands pre-scaled for exp2
#define KSC 0.04508422002778011f

typedef float              f32x4    __attribute__((ext_vector_type(4)));
typedef float              f32x16   __attribute__((ext_vector_type(16)));
typedef __bf16             bf16x8   __attribute__((ext_vector_type(8)));
typedef unsigned short     ushort8v __attribute__((ext_vector_type(8)));
typedef unsigned long long u64;

union FragU { ushort8v u; bf16x8 b; };
union BFrag { unsigned u32[4]; bf16x8 b; };

__device__ __forceinline__ unsigned short f2b(float f) {
  union { __hip_bfloat16 h; unsigned short u; } c;
  c.h = __float2bfloat16(f);
  return c.u;
}

__device__ __forceinline__ unsigned int cvt_pk_bf16(float lo, float hi) {
  unsigned int r;
  asm("v_cvt_pk_bf16_f32 %0, %1, %2" : "=v"(r) : "v"(lo), "v"(hi));
  return r;
}

#define PSWAP(a, b) asm("v_permlane32_swap_b32 %0, %1" : "+v"(a), "+v"(b))

#define GLD16(g, l)                                                            \
  __builtin_amdgcn_global_load_lds(                                            \
      (__attribute__((address_space(1))) void*)(g),                            \
      (__attribute__((address_space(3))) void*)(l), 16, 0, 0)

// ------------------------------------------------------- fused prep kernel
__global__ __launch_bounds__(256) void prep(
    const float* __restrict__ Wo, unsigned short* __restrict__ Wb,
    const float* __restrict__ Kg, unsigned short* __restrict__ Kb,
    const float* __restrict__ Vg, unsigned short* __restrict__ Vt,
    const int* __restrict__ Mg,   u64* __restrict__ Mb)
{
  const int bid = blockIdx.x;
  const int tid = threadIdx.x;
  if (bid < 2560) {
    const float* X = (bid < 512) ? Wo : Kg;
    unsigned short* Y = (bid < 512) ? Wb : Kb;
    const int bb = (bid < 512) ? bid : bid - 512;
    const size_t i = ((size_t)bb * 256 + tid) * 8;
    float4 a = *reinterpret_cast<const float4*>(X + i);
    float4 b = *reinterpret_cast<const float4*>(X + i + 4);
    ushort8v u;
    u[0] = f2b(a.x); u[1] = f2b(a.y); u[2] = f2b(a.z); u[3] = f2b(a.w);
    u[4] = f2b(b.x); u[5] = f2b(b.y); u[6] = f2b(b.z); u[7] = f2b(b.w);
    *reinterpret_cast<ushort8v*>(Y + i) = u;
  } else if (bid < 3584) {
    __shared__ unsigned short T[64][72];
    const int b2 = bid - 2560;
    const int sb = b2 & 31, h = (b2 >> 5) & 15, n = b2 >> 9;
    const int r = tid >> 2, cb = (tid & 3) * 16;
    const float* src = Vg + ((size_t)(n * S_LEN + sb * 64 + r)) * EMB + h * DHEAD + cb;
    ushort8v u0, u1;
#pragma unroll
    for (int j = 0; j < 2; ++j) {
      float4 x = *reinterpret_cast<const float4*>(src + j * 4);
      u0[j*4+0] = f2b(x.x); u0[j*4+1] = f2b(x.y); u0[j*4+2] = f2b(x.z); u0[j*4+3] = f2b(x.w);
      float4 y = *reinterpret_cast<const float4*>(src + 8 + j * 4);
      u1[j*4+0] = f2b(y.x); u1[j*4+1] = f2b(y.y); u1[j*4+2] = f2b(y.z); u1[j*4+3] = f2b(y.w);
    }
    *reinterpret_cast<ushort8v*>(&T[r][cb])     = u0;
    *reinterpret_cast<ushort8v*>(&T[r][cb + 8]) = u1;
    __syncthreads();
    const int d = tid >> 2, sc_ = (tid & 3) * 16;
    ushort8v o0, o1;
#pragma unroll
    for (int j = 0; j < 8; ++j) { o0[j] = T[sc_ + j][d]; o1[j] = T[sc_ + 8 + j][d]; }
    unsigned short* dst = Vt + ((size_t)((n * NHEAD + h) * DHEAD + d)) * S_LEN + sb * 64 + sc_;
    *reinterpret_cast<ushort8v*>(dst)     = o0;
    *reinterpret_cast<ushort8v*>(dst + 8) = o1;
  } else {
    const int b3 = bid - 3584;
    const size_t base = (size_t)b3 * 1024 + (tid >> 6) * 256;
    const int l = tid & 63;
#pragma unroll
    for (int j = 0; j < 4; ++j) {
      const int v = Mg[base + j * 64 + l];
      u64 bj = __ballot(v != 0);
      if (l == 0) Mb[base / 64 + j] = bj;
    }
  }
}

// ---------------------------------------------------------------- attention
__global__ __launch_bounds__(512)
__attribute__((amdgpu_waves_per_eu(4, 4)))
void attn_fwd(
    const unsigned short* __restrict__ Kb,   // bf16 [n][s][E]
    const unsigned short* __restrict__ Vtg,  // bf16 [n][h][d][s]
    const float* __restrict__ Qg,            // f32  [n][s][E]
    const u64* __restrict__ Mbit,            // [n][s][32]
    unsigned short* __restrict__ Og)         // bf16 [n][s][E]
{
  __shared__ __attribute__((aligned(16))) char SMEM[65536];

  const int bid = blockIdx.x;
  const int qb = bid & 15, h = (bid >> 4) & 15, n = bid >> 8;
  const int nh = n * NHEAD + h;
  const int tid = threadIdx.x;
  const int w = tid >> 6, sp = w >> 2, wq = w & 3;
  const int l = tid & 63, q5 = l & 31, hi = l >> 5;
  const int hi4 = hi * 4;
  const int q0w = qb * 128 + wq * 32;
  const int qg = q0w + q5;

  // Q fragments pre-scaled by log2e/32 (exp2 input comes straight from MFMA)
  FragU qf[4];
  {
    const float* qp = Qg + ((size_t)(n * S_LEN + qg)) * EMB + h * DHEAD + hi * 8;
#pragma unroll
    for (int s = 0; s < 4; ++s) {
      float4 a = *reinterpret_cast<const float4*>(qp + s * 16);
      float4 b = *reinterpret_cast<const float4*>(qp + s * 16 + 4);
      ushort8v u;
      u[0] = f2b(a.x * KSC); u[1] = f2b(a.y * KSC); u[2] = f2b(a.z * KSC); u[3] = f2b(a.w * KSC);
      u[4] = f2b(b.x * KSC); u[5] = f2b(b.y * KSC); u[6] = f2b(b.z * KSC); u[7] = f2b(b.w * KSC);
      qf[s].u = u;
    }
  }

  FragU ones;
#pragma unroll
  for (int j = 0; j < 8; ++j) ones.u[j] = 0x3F80;

  f32x16 acc0 = {}, acc1 = {}, racc = {};

  const int t8 = tid & 255;
  const int srow = t8 >> 3, sc = t8 & 7;
  const char* kbase = (const char*)Kb +
      ((size_t)(n * S_LEN + sp * 1024 + srow)) * 2048 + h * 128 +
      ((sc * 16) ^ ((srow & 7) << 4));
  const char* vbase = (const char*)Vtg +
      ((size_t)(nh * DHEAD + srow)) * 4096 + sp * 2048 +
      ((sc * 16) ^ ((srow & 7) << 4));

  char* Ksp = SMEM + sp * 16384;
  char* Vsp = SMEM + 32768 + sp * 16384;
  const int fsw = (l & 7) << 4;

  const u64* Mq = Mbit + ((size_t)(n * S_LEN + qg)) * 32 + sp * 16;
  u64 mq_cur = Mq[0];

#define ATTN_STAGE(BUF, IT) do {                                               \
    GLD16(kbase + (size_t)(IT) * 131072,          Ksp + (BUF) * 8192 + t8 * 16); \
    GLD16(kbase + (size_t)(IT) * 131072 + 65536,  Ksp + (BUF) * 8192 + 4096 + t8 * 16); \
    GLD16(vbase + (size_t)(IT) * 128,             Vsp + (BUF) * 8192 + t8 * 16); \
    GLD16(vbase + (size_t)(IT) * 128 + 131072,    Vsp + (BUF) * 8192 + 4096 + t8 * 16); \
  } while (0)

#define ATTN_TILE(BUF, IT) do {                                                \
    __syncthreads();                                                           \
    if ((IT) + 1 < 16) ATTN_STAGE((BUF) ^ 1, (IT) + 1);                        \
    const u64 mrow_ = mq_cur;                                                  \
    if ((IT) + 1 < 16) mq_cur = Mq[(IT) + 1];                                  \
    /* -- phase 1: QK^T for BOTH kv-blocks (8 independent MFMAs) -- */         \
    f32x16 Sb0 = {}, Sb1 = {};                                                 \
    _Pragma("unroll") for (int s = 0; s < 4; ++s) {                            \
      FragU kf0_, kf1_;                                                        \
      kf0_.u = *reinterpret_cast<const ushort8v*>(                             \
          Ksp + (BUF) * 8192 + (q5 * 128 + ((s * 32 + hi * 16) ^ fsw)));       \
      kf1_.u = *reinterpret_cast<const ushort8v*>(                             \
          Ksp + (BUF) * 8192 + ((32 + q5) * 128 + ((s * 32 + hi * 16) ^ fsw)));\
      Sb0 = __builtin_amdgcn_mfma_f32_32x32x16_bf16(kf0_.b, qf[s].b, Sb0, 0, 0, 0); \
      Sb1 = __builtin_amdgcn_mfma_f32_32x32x16_bf16(kf1_.b, qf[s].b, Sb1, 0, 0, 0); \
    }                                                                          \
    /* -- phase 2: softmax both blocks (VALU/trans only) -- */                 \
    unsigned UA[8], UB[8];                                                     \
    {                                                                          \
      const unsigned mA_ = (unsigned)mrow_;                                    \
      const unsigned mB_ = (unsigned)(mrow_ >> 32);                            \
      _Pragma("unroll") for (int t = 0; t < 4; ++t) {                          \
        const unsigned nA_ = mA_ >> (8 * t + hi4);                             \
        const unsigned nB_ = mB_ >> (8 * t + hi4);                             \
        float pA_[4], pB_[4];                                                  \
        _Pragma("unroll") for (int e = 0; e < 4; ++e) {                        \
          const int r = 4 * t + e;                                             \
          float eA_ = __builtin_amdgcn_exp2f(Sb0[r]);                          \
          float eB_ = __builtin_amdgcn_exp2f(Sb1[r]);                          \
          pA_[e] = __uint_as_float(__float_as_uint(eA_) &                      \
                   (unsigned)((int)(nA_ << (31 - e)) >> 31));                  \
          pB_[e] = __uint_as_float(__float_as_uint(eB_) &                      \
                   (unsigned)((int)(nB_ << (31 - e)) >> 31));                  \
        }                                                                      \
        UA[2*t]   = cvt_pk_bf16(pA_[0], pA_[1]);                               \
        UA[2*t+1] = cvt_pk_bf16(pA_[2], pA_[3]);                               \
        UB[2*t]   = cvt_pk_bf16(pB_[0], pB_[1]);                               \
        UB[2*t+1] = cvt_pk_bf16(pB_[2], pB_[3]);                               \
      }                                                                        \
      PSWAP(UA[0], UA[2]); PSWAP(UA[1], UA[3]);                                \
      PSWAP(UA[4], UA[6]); PSWAP(UA[5], UA[7]);                                \
      PSWAP(UB[0], UB[2]); PSWAP(UB[1], UB[3]);                                \
      PSWAP(UB[4], UB[6]); PSWAP(UB[5], UB[7]);                                \
    }                                                                          \
    BFrag FA0, FA1, FB0, FB1;                                                  \
    FA0.u32[0]=UA[0]; FA0.u32[1]=UA[1]; FA0.u32[2]=UA[2]; FA0.u32[3]=UA[3];    \
    FA1.u32[0]=UA[4]; FA1.u32[1]=UA[5]; FA1.u32[2]=UA[6]; FA1.u32[3]=UA[7];    \
    FB0.u32[0]=UB[0]; FB0.u32[1]=UB[1]; FB0.u32[2]=UB[2]; FB0.u32[3]=UB[3];    \
    FB1.u32[0]=UB[4]; FB1.u32[1]=UB[5]; FB1.u32[2]=UB[6]; FB1.u32[3]=UB[7];    \
    /* -- phase 3: rowsum + PV (12 MFMAs, independent chains) -- */            \
    racc = __builtin_amdgcn_mfma_f32_32x32x16_bf16(ones.b, FA0.b, racc, 0, 0, 0); \
    racc = __builtin_amdgcn_mfma_f32_32x32x16_bf16(ones.b, FA1.b, racc, 0, 0, 0); \
    racc = __builtin_amdgcn_mfma_f32_32x32x16_bf16(ones.b, FB0.b, racc, 0, 0, 0); \
    racc = __builtin_amdgcn_mfma_f32_32x32x16_bf16(ones.b, FB1.b, racc, 0, 0, 0); \
    _Pragma("unroll") for (int db = 0; db < 2; ++db) {                         \
      FragU v0_, v1_, v2_, v3_;                                                \
      v0_.u = *reinterpret_cast<const ushort8v*>(                              \
          Vsp + (BUF) * 8192 + ((db * 32 + q5) * 128 + ((0 * 32 + hi * 16) ^ fsw))); \
      v1_.u = *reinterpret_cast<const ushort8v*>(                              \
          Vsp + (BUF) * 8192 + ((db * 32 + q5) * 128 + ((1 * 32 + hi * 16) ^ fsw))); \
      v2_.u = *reinterpret_cast<const ushort8v*>(                              \
          Vsp + (BUF) * 8192 + ((db * 32 + q5) * 128 + ((2 * 32 + hi * 16) ^ fsw))); \
      v3_.u = *reinterpret_cast<const ushort8v*>(                              \
          Vsp + (BUF) * 8192 + ((db * 32 + q5) * 128 + ((3 * 32 + hi * 16) ^ fsw))); \
      if (db == 0) {                                                           \
        acc0 = __builtin_amdgcn_mfma_f32_32x32x16_bf16(v0_.b, FA0.b, acc0, 0, 0, 0); \
        acc0 = __builtin_amdgcn_mfma_f32_32x32x16_bf16(v1_.b, FA1.b, acc0, 0, 0, 0); \
        acc0 = __builtin_amdgcn_mfma_f32_32x32x16_bf16(v2_.b, FB0.b, acc0, 0, 0, 0); \
        acc0 = __builtin_amdgcn_mfma_f32_32x32x16_bf16(v3_.b, FB1.b, acc0, 0, 0, 0); \
      } else {                                                                 \
        acc1 = __builtin_amdgcn_mfma_f32_32x32x16_bf16(v0_.b, FA0.b, acc1, 0, 0, 0); \
        acc1 = __builtin_amdgcn_mfma_f32_32x32x16_bf16(v1_.b, FA1.b, acc1, 0, 0, 0); \
        acc1 = __builtin_amdgcn_mfma_f32_32x32x16_bf16(v2_.b, FB0.b, acc1, 0, 0, 0); \
        acc1 = __builtin_amdgcn_mfma_f32_32x32x16_bf16(v3_.b, FB1.b, acc1, 0, 0, 0); \
      }                                                                        \
    }                                                                          \
  } while (0)

  ATTN_STAGE(0, 0);
  for (int it = 0; it < 16; it += 2) {
    ATTN_TILE(0, it);
    ATTN_TILE(1, it + 1);
  }

  // ---- combine splits + normalize + store ----
  const float rs = racc[0];   // ones-MFMA: every row holds the full kv-sum
  const int esw = (l & 7) << 4;

  __syncthreads();
  if (sp == 1) {
#pragma unroll
    for (int i = 0; i < 4; ++i) {
      f32x4 v0 = (f32x4){acc0[4*i], acc0[4*i+1], acc0[4*i+2], acc0[4*i+3]};
      f32x4 v1 = (f32x4){acc1[4*i], acc1[4*i+1], acc1[4*i+2], acc1[4*i+3]};
      *reinterpret_cast<f32x4*>(SMEM + wq * 8192 + l * 128 + ((i * 16) ^ esw))      = v0;
      *reinterpret_cast<f32x4*>(SMEM + wq * 8192 + l * 128 + ((64 + i * 16) ^ esw)) = v1;
    }
    *reinterpret_cast<float*>(SMEM + 32768 + wq * 256 + l * 4) = rs;
  }
  __syncthreads();
  if (sp == 0) {
    const float ors = *reinterpret_cast<const float*>(SMEM + 32768 + wq * 256 + l * 4);
    const float rin = 1.0f / (rs + ors);
    unsigned short* orow = Og + ((size_t)(n * S_LEN + qg)) * EMB + h * DHEAD + hi4;
#pragma unroll
    for (int db = 0; db < 2; ++db) {
#pragma unroll
      for (int t = 0; t < 4; ++t) {
        f32x4 pa = *reinterpret_cast<const f32x4*>(
            SMEM + wq * 8192 + l * 128 + ((db * 64 + t * 16) ^ esw));
        float a0, a1, a2, a3;
        if (db == 0) {
          a0 = (acc0[4*t]   + pa[0]) * rin; a1 = (acc0[4*t+1] + pa[1]) * rin;
          a2 = (acc0[4*t+2] + pa[2]) * rin; a3 = (acc0[4*t+3] + pa[3]) * rin;
        } else {
          a0 = (acc1[4*t]   + pa[0]) * rin; a1 = (acc1[4*t+1] + pa[1]) * rin;
          a2 = (acc1[4*t+2] + pa[2]) * rin; a3 = (acc1[4*t+3] + pa[3]) * rin;
        }
        uint2 pk;
        pk.x = cvt_pk_bf16(a0, a1);
        pk.y = cvt_pk_bf16(a2, a3);
        *reinterpret_cast<uint2*>(orow + db * 32 + t * 8) = pk;
      }
    }
  }
}

// ---------------------------------------------------------------- projection
// 128x128 tile, BK=64, 4 waves in 2x2, each wave 64x64 out (acc[4][4]).
__global__ __launch_bounds__(256, 2) void out_proj(
    const unsigned short* __restrict__ A,   // bf16 [4096][1024]
    const unsigned short* __restrict__ W,   // bf16 [1024][1024]
    const float* __restrict__ bias,
    float* __restrict__ Y)                  // f32 [4096][1024]
{
  __shared__ __attribute__((aligned(16))) char PSM[65536];  // A[2][16K] @0, B[2][16K] @32K

  const int bid = blockIdx.x;
  const int nb = bid & 7, mb = bid >> 3;   // mb 0..31, nb 0..7
  const int tid = threadIdx.x;
  const int w = tid >> 6, wr = w >> 1, wc = w & 1;
  const int l = tid & 63, lg = l >> 4, li = l & 15;
  const int m0 = mb * 128, n0 = nb * 128;

  f32x4 acc[4][4];
#pragma unroll
  for (int mi = 0; mi < 4; ++mi)
#pragma unroll
    for (int ci = 0; ci < 4; ++ci) acc[mi][ci] = (f32x4){0.f, 0.f, 0.f, 0.f};

  const int srow = tid >> 3;            // 0..31
  const int sch  = (tid & 7) * 16;
  const int ssw  = (srow & 7) << 4;
  const char* abase = (const char*)A + ((size_t)(m0 + srow)) * 2048 + (sch ^ ssw);
  const char* bbase = (const char*)W + ((size_t)(n0 + srow)) * 2048 + (sch ^ ssw);
  const int rsw = (li & 7) << 4;

  char* Asm = PSM;
  char* Bsm = PSM + 32768;

#define PROJ_STAGE(BUF, KK) do {                                               \
    _Pragma("unroll") for (int j = 0; j < 4; ++j) {                            \
      GLD16(abase + (size_t)j * 65536 + (KK) * 128,                            \
            Asm + (BUF) * 16384 + j * 4096 + tid * 16);                        \
      GLD16(bbase + (size_t)j * 65536 + (KK) * 128,                            \
            Bsm + (BUF) * 16384 + j * 4096 + tid * 16);                        \
    }                                                                          \
  } while (0)

#define PROJ_TILE(BUF, KK) do {                                                \
    __syncthreads();                                                           \
    if ((KK) + 1 < 16) PROJ_STAGE((BUF) ^ 1, (KK) + 1);                        \
    _Pragma("unroll") for (int s = 0; s < 2; ++s) {                            \
      FragU af_[4], bf_[4];                                                    \
      _Pragma("unroll") for (int mi = 0; mi < 4; ++mi)                         \
        af_[mi].u = *reinterpret_cast<const ushort8v*>(                        \
            Asm + (BUF) * 16384 +                                              \
            ((wr * 64 + mi * 16 + li) * 128 + ((s * 64 + lg * 16) ^ rsw)));    \
      _Pragma("unroll") for (int ci = 0; ci < 4; ++ci)                         \
        bf_[ci].u = *reinterpret_cast<const ushort8v*>(                        \
            Bsm + (BUF) * 16384 +                                              \
            ((wc * 64 + ci * 16 + li) * 128 + ((s * 64 + lg * 16) ^ rsw)));    \
      _Pragma("unroll") for (int mi = 0; mi < 4; ++mi)                         \
        _Pragma("unroll") for (int ci = 0; ci < 4; ++ci)                       \
          acc[mi][ci] = __builtin_amdgcn_mfma_f32_16x16x32_bf16(               \
              af_[mi].b, bf_[ci].b, acc[mi][ci], 0, 0, 0);                     \
    }                                                                          \
  } while (0)

  PROJ_STAGE(0, 0);
  for (int kk = 0; kk < 16; kk += 2) {
    PROJ_TILE(0, kk);
    PROJ_TILE(1, kk + 1);
  }

#pragma unroll
  for (int ci = 0; ci < 4; ++ci) {
    const int col = n0 + wc * 64 + ci * 16 + li;
    const float bv = bias[col];
#pragma unroll
    for (int mi = 0; mi < 4; ++mi) {
#pragma unroll
      for (int r = 0; r < 4; ++r) {
        const int row = m0 + wr * 64 + mi * 16 + lg * 4 + r;
        Y[(size_t)row * EMB + col] = acc[mi][ci][r] + bv;
      }
    }
  }
}

// ---------------------------------------------------------------- launch
extern "C" void kernel_launch(void* const* d_in, const int* in_sizes, int n_in,
                              void* d_out, int out_size, void* d_ws, size_t ws_size,
                              hipStream_t stream) {
  const float* Vg = (const float*)d_in[0];
  const float* Kg = (const float*)d_in[1];
  const float* Qg = (const float*)d_in[2];
  const int*   Mg = (const int*)d_in[3];
  const float* Wo = (const float*)d_in[4];
  const float* bo = (const float*)d_in[5];
  float* Y = (float*)d_out;

  char* ws = (char*)d_ws;
  unsigned short* Og   = (unsigned short*)(ws);                       //  8 MB
  unsigned short* Wb   = (unsigned short*)(ws + (8u << 20));          //  2 MB
  unsigned short* Kb16 = (unsigned short*)(ws + (10u << 20));         //  8 MB
  unsigned short* Vt   = (unsigned short*)(ws + (18u << 20));         //  8 MB
  u64*            Mbit = (u64*)(ws + (26u << 20));                    //  1 MB

  hipLaunchKernelGGL(prep, dim3(11776), dim3(256), 0, stream,
                     Wo, Wb, Kg, Kb16, Vg, Vt, Mg, Mbit);
  hipLaunchKernelGGL(attn_fwd, dim3(NBATCH * NHEAD * (S_LEN / 128)), dim3(512), 0, stream,
                     Kb16, Vt, Qg, Mbit, Og);
  hipLaunchKernelGGL(out_proj, dim3((NBATCH * S_LEN / 128) * (EMB / 128)), dim3(256), 0, stream,
                     Og, Wb, bo, Y);
}

// Round 14
// 87.486 us; speedup vs baseline: 1.9524x; 1.0834x over previous
//
#include <hip/hip_runtime.h>
#include <hip/hip_bf16.h>

// SelfAttention: N=2, S=2048, E=1024, H=16, D=64.
// Round 14: best-of merge. attn = round 10 verbatim (58.4us: 32x32x16 MFMA,
// KV-split 8-wave, pre-scaled Q, ones-MFMA rowsum, sign-AND masking, cvt_pk +
// permlane32_swap in-register P, setprio clusters). out_proj = round 13
// (128x128xBK64, 2x MFMA:DS). prep = round 10. Wide-phase experiments (r11/
// r13) abandoned: compiler pins 64 VGPR at 512 threads and spills.

#define S_LEN  2048
#define EMB    1024
#define NHEAD  16
#define DHEAD  64
#define NBATCH 2

// log2(e)/32: folded into Q so QK^T lands pre-scaled for exp2
#define KSC 0.04508422002778011f

typedef float              f32x4    __attribute__((ext_vector_type(4)));
typedef float              f32x16   __attribute__((ext_vector_type(16)));
typedef __bf16             bf16x8   __attribute__((ext_vector_type(8)));
typedef unsigned short     ushort8v __attribute__((ext_vector_type(8)));
typedef unsigned long long u64;

union FragU { ushort8v u; bf16x8 b; };
union BFrag { unsigned u32[4]; bf16x8 b; };

__device__ __forceinline__ unsigned short f2b(float f) {
  union { __hip_bfloat16 h; unsigned short u; } c;
  c.h = __float2bfloat16(f);
  return c.u;
}

__device__ __forceinline__ unsigned int cvt_pk_bf16(float lo, float hi) {
  unsigned int r;
  asm("v_cvt_pk_bf16_f32 %0, %1, %2" : "=v"(r) : "v"(lo), "v"(hi));
  return r;
}

#define PSWAP(a, b) asm("v_permlane32_swap_b32 %0, %1" : "+v"(a), "+v"(b))

#define GLD16(g, l)                                                            \
  __builtin_amdgcn_global_load_lds(                                            \
      (__attribute__((address_space(1))) void*)(g),                            \
      (__attribute__((address_space(3))) void*)(l), 16, 0, 0)

// ------------------------------------------------------- fused prep kernel
__global__ __launch_bounds__(256) void prep(
    const float* __restrict__ Wo, unsigned short* __restrict__ Wb,
    const float* __restrict__ Kg, unsigned short* __restrict__ Kb,
    const float* __restrict__ Vg, unsigned short* __restrict__ Vt,
    const int* __restrict__ Mg,   u64* __restrict__ Mb)
{
  const int bid = blockIdx.x;
  const int tid = threadIdx.x;
  if (bid < 2560) {
    const float* X = (bid < 512) ? Wo : Kg;
    unsigned short* Y = (bid < 512) ? Wb : Kb;
    const int bb = (bid < 512) ? bid : bid - 512;
    const size_t i = ((size_t)bb * 256 + tid) * 8;
    float4 a = *reinterpret_cast<const float4*>(X + i);
    float4 b = *reinterpret_cast<const float4*>(X + i + 4);
    ushort8v u;
    u[0] = f2b(a.x); u[1] = f2b(a.y); u[2] = f2b(a.z); u[3] = f2b(a.w);
    u[4] = f2b(b.x); u[5] = f2b(b.y); u[6] = f2b(b.z); u[7] = f2b(b.w);
    *reinterpret_cast<ushort8v*>(Y + i) = u;
  } else if (bid < 3584) {
    __shared__ unsigned short T[64][72];
    const int b2 = bid - 2560;
    const int sb = b2 & 31, h = (b2 >> 5) & 15, n = b2 >> 9;
    const int r = tid >> 2, cb = (tid & 3) * 16;
    const float* src = Vg + ((size_t)(n * S_LEN + sb * 64 + r)) * EMB + h * DHEAD + cb;
    ushort8v u0, u1;
#pragma unroll
    for (int j = 0; j < 2; ++j) {
      float4 x = *reinterpret_cast<const float4*>(src + j * 4);
      u0[j*4+0] = f2b(x.x); u0[j*4+1] = f2b(x.y); u0[j*4+2] = f2b(x.z); u0[j*4+3] = f2b(x.w);
      float4 y = *reinterpret_cast<const float4*>(src + 8 + j * 4);
      u1[j*4+0] = f2b(y.x); u1[j*4+1] = f2b(y.y); u1[j*4+2] = f2b(y.z); u1[j*4+3] = f2b(y.w);
    }
    *reinterpret_cast<ushort8v*>(&T[r][cb])     = u0;
    *reinterpret_cast<ushort8v*>(&T[r][cb + 8]) = u1;
    __syncthreads();
    const int d = tid >> 2, sc_ = (tid & 3) * 16;
    ushort8v o0, o1;
#pragma unroll
    for (int j = 0; j < 8; ++j) { o0[j] = T[sc_ + j][d]; o1[j] = T[sc_ + 8 + j][d]; }
    unsigned short* dst = Vt + ((size_t)((n * NHEAD + h) * DHEAD + d)) * S_LEN + sb * 64 + sc_;
    *reinterpret_cast<ushort8v*>(dst)     = o0;
    *reinterpret_cast<ushort8v*>(dst + 8) = o1;
  } else {
    const int b3 = bid - 3584;
    const size_t base = (size_t)b3 * 1024 + (tid >> 6) * 256;
    const int l = tid & 63;
#pragma unroll
    for (int j = 0; j < 4; ++j) {
      const int v = Mg[base + j * 64 + l];
      u64 bj = __ballot(v != 0);
      if (l == 0) Mb[base / 64 + j] = bj;
    }
  }
}

// ---------------------------------------------------------------- attention
__global__ __launch_bounds__(512, 4) void attn_fwd(
    const unsigned short* __restrict__ Kb,   // bf16 [n][s][E]
    const unsigned short* __restrict__ Vtg,  // bf16 [n][h][d][s]
    const float* __restrict__ Qg,            // f32  [n][s][E]
    const u64* __restrict__ Mbit,            // [n][s][32]
    unsigned short* __restrict__ Og)         // bf16 [n][s][E]
{
  __shared__ __attribute__((aligned(16))) char SMEM[65536];

  const int bid = blockIdx.x;
  const int qb = bid & 15, h = (bid >> 4) & 15, n = bid >> 8;
  const int nh = n * NHEAD + h;
  const int tid = threadIdx.x;
  const int w = tid >> 6, sp = w >> 2, wq = w & 3;
  const int l = tid & 63, q5 = l & 31, hi = l >> 5;
  const int hi4 = hi * 4;
  const int q0w = qb * 128 + wq * 32;
  const int qg = q0w + q5;

  // Q fragments pre-scaled by log2e/32 (exp2 input comes straight from MFMA)
  FragU qf[4];
  {
    const float* qp = Qg + ((size_t)(n * S_LEN + qg)) * EMB + h * DHEAD + hi * 8;
#pragma unroll
    for (int s = 0; s < 4; ++s) {
      float4 a = *reinterpret_cast<const float4*>(qp + s * 16);
      float4 b = *reinterpret_cast<const float4*>(qp + s * 16 + 4);
      ushort8v u;
      u[0] = f2b(a.x * KSC); u[1] = f2b(a.y * KSC); u[2] = f2b(a.z * KSC); u[3] = f2b(a.w * KSC);
      u[4] = f2b(b.x * KSC); u[5] = f2b(b.y * KSC); u[6] = f2b(b.z * KSC); u[7] = f2b(b.w * KSC);
      qf[s].u = u;
    }
  }

  FragU ones;
#pragma unroll
  for (int j = 0; j < 8; ++j) ones.u[j] = 0x3F80;

  f32x16 acc0 = {}, acc1 = {}, racc = {};

  const int t8 = tid & 255;
  const int srow = t8 >> 3, sc = t8 & 7;
  const char* kbase = (const char*)Kb +
      ((size_t)(n * S_LEN + sp * 1024 + srow)) * 2048 + h * 128 +
      ((sc * 16) ^ ((srow & 7) << 4));
  const char* vbase = (const char*)Vtg +
      ((size_t)(nh * DHEAD + srow)) * 4096 + sp * 2048 +
      ((sc * 16) ^ ((srow & 7) << 4));

  char* Ksp = SMEM + sp * 16384;
  char* Vsp = SMEM + 32768 + sp * 16384;
  const int fsw = (l & 7) << 4;

  const u64* Mq = Mbit + ((size_t)(n * S_LEN + qg)) * 32 + sp * 16;
  u64 mq_cur = Mq[0];

#define ATTN_STAGE(BUF, IT) do {                                               \
    GLD16(kbase + (size_t)(IT) * 131072,          Ksp + (BUF) * 8192 + t8 * 16); \
    GLD16(kbase + (size_t)(IT) * 131072 + 65536,  Ksp + (BUF) * 8192 + 4096 + t8 * 16); \
    GLD16(vbase + (size_t)(IT) * 128,             Vsp + (BUF) * 8192 + t8 * 16); \
    GLD16(vbase + (size_t)(IT) * 128 + 131072,    Vsp + (BUF) * 8192 + 4096 + t8 * 16); \
  } while (0)

#define ATTN_TILE(BUF, IT) do {                                                \
    __syncthreads();                                                           \
    if ((IT) + 1 < 16) ATTN_STAGE((BUF) ^ 1, (IT) + 1);                        \
    const u64 mrow_ = mq_cur;                                                  \
    if ((IT) + 1 < 16) mq_cur = Mq[(IT) + 1];                                  \
    _Pragma("unroll") for (int b = 0; b < 2; ++b) {                            \
      f32x16 Sb = {};                                                          \
      __builtin_amdgcn_s_setprio(1);                                           \
      _Pragma("unroll") for (int s = 0; s < 4; ++s) {                          \
        FragU kf_;                                                             \
        kf_.u = *reinterpret_cast<const ushort8v*>(                            \
            Ksp + (BUF) * 8192 + ((b * 32 + q5) * 128 + ((s * 32 + hi * 16) ^ fsw))); \
        Sb = __builtin_amdgcn_mfma_f32_32x32x16_bf16(kf_.b, qf[s].b, Sb, 0, 0, 0); \
      }                                                                        \
      __builtin_amdgcn_s_setprio(0);                                           \
      const unsigned m32_ = b ? (unsigned)(mrow_ >> 32) : (unsigned)mrow_;     \
      float p_[16];                                                            \
      _Pragma("unroll") for (int t = 0; t < 4; ++t) {                          \
        const unsigned nib_ = m32_ >> (8 * t + hi4);                           \
        _Pragma("unroll") for (int e = 0; e < 4; ++e) {                        \
          const int r = 4 * t + e;                                             \
          float ex_ = __builtin_amdgcn_exp2f(Sb[r]);                           \
          const unsigned sm_ = (unsigned)((int)(nib_ << (31 - e)) >> 31);      \
          p_[r] = __uint_as_float(__float_as_uint(ex_) & sm_);                 \
        }                                                                      \
      }                                                                        \
      unsigned U0 = cvt_pk_bf16(p_[0],  p_[1]),  U1 = cvt_pk_bf16(p_[2],  p_[3]); \
      unsigned U2 = cvt_pk_bf16(p_[4],  p_[5]),  U3 = cvt_pk_bf16(p_[6],  p_[7]); \
      unsigned U4 = cvt_pk_bf16(p_[8],  p_[9]),  U5 = cvt_pk_bf16(p_[10], p_[11]); \
      unsigned U6 = cvt_pk_bf16(p_[12], p_[13]), U7 = cvt_pk_bf16(p_[14], p_[15]); \
      PSWAP(U0, U2); PSWAP(U1, U3); PSWAP(U4, U6); PSWAP(U5, U7);              \
      BFrag F0, F1;                                                            \
      F0.u32[0] = U0; F0.u32[1] = U1; F0.u32[2] = U2; F0.u32[3] = U3;          \
      F1.u32[0] = U4; F1.u32[1] = U5; F1.u32[2] = U6; F1.u32[3] = U7;          \
      __builtin_amdgcn_s_setprio(1);                                           \
      racc = __builtin_amdgcn_mfma_f32_32x32x16_bf16(ones.b, F0.b, racc, 0, 0, 0); \
      racc = __builtin_amdgcn_mfma_f32_32x32x16_bf16(ones.b, F1.b, racc, 0, 0, 0); \
      _Pragma("unroll") for (int db = 0; db < 2; ++db) {                       \
        FragU vf0_, vf1_;                                                      \
        vf0_.u = *reinterpret_cast<const ushort8v*>(                           \
            Vsp + (BUF) * 8192 + ((db * 32 + q5) * 128 + (((2 * b) * 32 + hi * 16) ^ fsw))); \
        vf1_.u = *reinterpret_cast<const ushort8v*>(                           \
            Vsp + (BUF) * 8192 + ((db * 32 + q5) * 128 + (((2 * b + 1) * 32 + hi * 16) ^ fsw))); \
        if (db == 0) {                                                         \
          acc0 = __builtin_amdgcn_mfma_f32_32x32x16_bf16(vf0_.b, F0.b, acc0, 0, 0, 0); \
          acc0 = __builtin_amdgcn_mfma_f32_32x32x16_bf16(vf1_.b, F1.b, acc0, 0, 0, 0); \
        } else {                                                               \
          acc1 = __builtin_amdgcn_mfma_f32_32x32x16_bf16(vf0_.b, F0.b, acc1, 0, 0, 0); \
          acc1 = __builtin_amdgcn_mfma_f32_32x32x16_bf16(vf1_.b, F1.b, acc1, 0, 0, 0); \
        }                                                                      \
      }                                                                        \
      __builtin_amdgcn_s_setprio(0);                                           \
    }                                                                          \
  } while (0)

  ATTN_STAGE(0, 0);
  for (int it = 0; it < 16; it += 2) {
    ATTN_TILE(0, it);
    ATTN_TILE(1, it + 1);
  }

  // ---- combine splits + normalize + store ----
  const float rs = racc[0];   // ones-MFMA: every row holds the full kv-sum
  const int esw = (l & 7) << 4;

  __syncthreads();
  if (sp == 1) {
#pragma unroll
    for (int i = 0; i < 4; ++i) {
      f32x4 v0 = (f32x4){acc0[4*i], acc0[4*i+1], acc0[4*i+2], acc0[4*i+3]};
      f32x4 v1 = (f32x4){acc1[4*i], acc1[4*i+1], acc1[4*i+2], acc1[4*i+3]};
      *reinterpret_cast<f32x4*>(SMEM + wq * 8192 + l * 128 + ((i * 16) ^ esw))      = v0;
      *reinterpret_cast<f32x4*>(SMEM + wq * 8192 + l * 128 + ((64 + i * 16) ^ esw)) = v1;
    }
    *reinterpret_cast<float*>(SMEM + 32768 + wq * 256 + l * 4) = rs;
  }
  __syncthreads();
  if (sp == 0) {
    const float ors = *reinterpret_cast<const float*>(SMEM + 32768 + wq * 256 + l * 4);
    const float rin = 1.0f / (rs + ors);
    unsigned short* orow = Og + ((size_t)(n * S_LEN + qg)) * EMB + h * DHEAD + hi4;
#pragma unroll
    for (int db = 0; db < 2; ++db) {
#pragma unroll
      for (int t = 0; t < 4; ++t) {
        f32x4 pa = *reinterpret_cast<const f32x4*>(
            SMEM + wq * 8192 + l * 128 + ((db * 64 + t * 16) ^ esw));
        float a0, a1, a2, a3;
        if (db == 0) {
          a0 = (acc0[4*t]   + pa[0]) * rin; a1 = (acc0[4*t+1] + pa[1]) * rin;
          a2 = (acc0[4*t+2] + pa[2]) * rin; a3 = (acc0[4*t+3] + pa[3]) * rin;
        } else {
          a0 = (acc1[4*t]   + pa[0]) * rin; a1 = (acc1[4*t+1] + pa[1]) * rin;
          a2 = (acc1[4*t+2] + pa[2]) * rin; a3 = (acc1[4*t+3] + pa[3]) * rin;
        }
        uint2 pk;
        pk.x = cvt_pk_bf16(a0, a1);
        pk.y = cvt_pk_bf16(a2, a3);
        *reinterpret_cast<uint2*>(orow + db * 32 + t * 8) = pk;
      }
    }
  }
}

// ---------------------------------------------------------------- projection
// 128x128 tile, BK=64, 4 waves in 2x2, each wave 64x64 out (acc[4][4]).
__global__ __launch_bounds__(256, 2) void out_proj(
    const unsigned short* __restrict__ A,   // bf16 [4096][1024]
    const unsigned short* __restrict__ W,   // bf16 [1024][1024]
    const float* __restrict__ bias,
    float* __restrict__ Y)                  // f32 [4096][1024]
{
  __shared__ __attribute__((aligned(16))) char PSM[65536];  // A[2][16K] @0, B[2][16K] @32K

  const int bid = blockIdx.x;
  const int nb = bid & 7, mb = bid >> 3;   // mb 0..31, nb 0..7
  const int tid = threadIdx.x;
  const int w = tid >> 6, wr = w >> 1, wc = w & 1;
  const int l = tid & 63, lg = l >> 4, li = l & 15;
  const int m0 = mb * 128, n0 = nb * 128;

  f32x4 acc[4][4];
#pragma unroll
  for (int mi = 0; mi < 4; ++mi)
#pragma unroll
    for (int ci = 0; ci < 4; ++ci) acc[mi][ci] = (f32x4){0.f, 0.f, 0.f, 0.f};

  const int srow = tid >> 3;            // 0..31
  const int sch  = (tid & 7) * 16;
  const int ssw  = (srow & 7) << 4;
  const char* abase = (const char*)A + ((size_t)(m0 + srow)) * 2048 + (sch ^ ssw);
  const char* bbase = (const char*)W + ((size_t)(n0 + srow)) * 2048 + (sch ^ ssw);
  const int rsw = (li & 7) << 4;

  char* Asm = PSM;
  char* Bsm = PSM + 32768;

#define PROJ_STAGE(BUF, KK) do {                                               \
    _Pragma("unroll") for (int j = 0; j < 4; ++j) {                            \
      GLD16(abase + (size_t)j * 65536 + (KK) * 128,                            \
            Asm + (BUF) * 16384 + j * 4096 + tid * 16);                        \
      GLD16(bbase + (size_t)j * 65536 + (KK) * 128,                            \
            Bsm + (BUF) * 16384 + j * 4096 + tid * 16);                        \
    }                                                                          \
  } while (0)

#define PROJ_TILE(BUF, KK) do {                                                \
    __syncthreads();                                                           \
    if ((KK) + 1 < 16) PROJ_STAGE((BUF) ^ 1, (KK) + 1);                        \
    _Pragma("unroll") for (int s = 0; s < 2; ++s) {                            \
      FragU af_[4], bf_[4];                                                    \
      _Pragma("unroll") for (int mi = 0; mi < 4; ++mi)                         \
        af_[mi].u = *reinterpret_cast<const ushort8v*>(                        \
            Asm + (BUF) * 16384 +                                              \
            ((wr * 64 + mi * 16 + li) * 128 + ((s * 64 + lg * 16) ^ rsw)));    \
      _Pragma("unroll") for (int ci = 0; ci < 4; ++ci)                         \
        bf_[ci].u = *reinterpret_cast<const ushort8v*>(                        \
            Bsm + (BUF) * 16384 +                                              \
            ((wc * 64 + ci * 16 + li) * 128 + ((s * 64 + lg * 16) ^ rsw)));    \
      _Pragma("unroll") for (int mi = 0; mi < 4; ++mi)                         \
        _Pragma("unroll") for (int ci = 0; ci < 4; ++ci)                       \
          acc[mi][ci] = __builtin_amdgcn_mfma_f32_16x16x32_bf16(               \
              af_[mi].b, bf_[ci].b, acc[mi][ci], 0, 0, 0);                     \
    }                                                                          \
  } while (0)

  PROJ_STAGE(0, 0);
  for (int kk = 0; kk < 16; kk += 2) {
    PROJ_TILE(0, kk);
    PROJ_TILE(1, kk + 1);
  }

#pragma unroll
  for (int ci = 0; ci < 4; ++ci) {
    const int col = n0 + wc * 64 + ci * 16 + li;
    const float bv = bias[col];
#pragma unroll
    for (int mi = 0; mi < 4; ++mi) {
#pragma unroll
      for (int r = 0; r < 4; ++r) {
        const int row = m0 + wr * 64 + mi * 16 + lg * 4 + r;
        Y[(size_t)row * EMB + col] = acc[mi][ci][r] + bv;
      }
    }
  }
}

// ---------------------------------------------------------------- launch
extern "C" void kernel_launch(void* const* d_in, const int* in_sizes, int n_in,
                              void* d_out, int out_size, void* d_ws, size_t ws_size,
                              hipStream_t stream) {
  const float* Vg = (const float*)d_in[0];
  const float* Kg = (const float*)d_in[1];
  const float* Qg = (const float*)d_in[2];
  const int*   Mg = (const int*)d_in[3];
  const float* Wo = (const float*)d_in[4];
  const float* bo = (const float*)d_in[5];
  float* Y = (float*)d_out;

  char* ws = (char*)d_ws;
  unsigned short* Og   = (unsigned short*)(ws);                       //  8 MB
  unsigned short* Wb   = (unsigned short*)(ws + (8u << 20));          //  2 MB
  unsigned short* Kb16 = (unsigned short*)(ws + (10u << 20));         //  8 MB
  unsigned short* Vt   = (unsigned short*)(ws + (18u << 20));         //  8 MB
  u64*            Mbit = (u64*)(ws + (26u << 20));                    //  1 MB

  hipLaunchKernelGGL(prep, dim3(11776), dim3(256), 0, stream,
                     Wo, Wb, Kg, Kb16, Vg, Vt, Mg, Mbit);
  hipLaunchKernelGGL(attn_fwd, dim3(NBATCH * NHEAD * (S_LEN / 128)), dim3(512), 0, stream,
                     Kb16, Vt, Qg, Mbit, Og);
  hipLaunchKernelGGL(out_proj, dim3((NBATCH * S_LEN / 128) * (EMB / 128)), dim3(256), 0, stream,
                     Og, Wb, bo, Y);
}